// Round 1
// baseline (545.929 us; speedup 1.0000x reference)
//
#include <hip/hip_runtime.h>

// Kuramoto-style graph interaction kernel, MI355X (gfx950).
// state: [N,64] f32; ind: [E,2] int32 (harness converts int64 -> int32);
// w1,b1,w2: [64] f32; b2: [1] f32. Output: [N,64] f32.
//
// Pipeline:
//   1) nstate = state / ||state||_row           (one wave per row)
//   2) per edge e: s = <nstate[src], nstate[dst]>
//      dE = sum_d gelu_tanh(s*w1[d]+b1[d]) * w2[d] + b2
//      atomicAdd acc[src] += dE * nstate[dst]; acc[dst] += dE * nstate[src]
//      (acc lives in d_out, zeroed each launch)
//   3) out = -acc + nstate * <nstate, acc>_row  (in place, one wave per row)

#define D 64

__device__ __forceinline__ float waveReduceSum64(float v) {
    // full 64-lane butterfly
    v += __shfl_xor(v, 32, 64);
    v += __shfl_xor(v, 16, 64);
    v += __shfl_xor(v, 8, 64);
    v += __shfl_xor(v, 4, 64);
    v += __shfl_xor(v, 2, 64);
    v += __shfl_xor(v, 1, 64);
    return v;
}

// JAX default gelu (approximate=True): 0.5*x*(1+tanh(sqrt(2/pi)*(x+0.044715 x^3)))
__device__ __forceinline__ float gelu_tanh(float x) {
    float t = 0.7978845608028654f * fmaf(0.044715f * x, x * x, x);
    // tanh via fast exp, overflow-safe: tanh(|t|) = (1-e^{-2|t|})/(1+e^{-2|t|})
    float e = __expf(-2.0f * fabsf(t));
    float th = (1.0f - e) / (1.0f + e);
    th = copysignf(th, t);
    return 0.5f * x * (1.0f + th);
}

__global__ void norm_kernel(const float* __restrict__ state,
                            float* __restrict__ nstate, int n_nodes) {
    int gid = blockIdx.x * blockDim.x + threadIdx.x;
    int row = gid >> 6;
    int lane = threadIdx.x & 63;
    if (row >= n_nodes) return;
    float v = state[row * D + lane];
    float ss = waveReduceSum64(v * v);
    float inv = 1.0f / sqrtf(ss);
    nstate[row * D + lane] = v * inv;
}

__global__ void edge_kernel(const float* __restrict__ nstate,
                            const int* __restrict__ ind,
                            const float* __restrict__ w1,
                            const float* __restrict__ b1,
                            const float* __restrict__ w2,
                            const float* __restrict__ b2,
                            float* __restrict__ acc, int n_edges) {
    int gid = blockIdx.x * blockDim.x + threadIdx.x;
    int edge = gid >> 6;
    int lane = threadIdx.x & 63;
    if (edge >= n_edges) return;

    const int2 e = ((const int2*)ind)[edge];  // (src, dst)
    int src = e.x, dst = e.y;

    float sv = nstate[src * D + lane];
    float dv = nstate[dst * D + lane];

    float s = waveReduceSum64(sv * dv);  // broadcast to all lanes

    // per-lane MLP column
    float x = fmaf(s, w1[lane], b1[lane]);
    float h = gelu_tanh(x) * w2[lane];
    float dE = waveReduceSum64(h) + b2[0];

    atomicAdd(&acc[src * D + lane], dE * dv);
    atomicAdd(&acc[dst * D + lane], dE * sv);
}

__global__ void final_kernel(const float* __restrict__ nstate,
                             float* __restrict__ out, int n_nodes) {
    int gid = blockIdx.x * blockDim.x + threadIdx.x;
    int row = gid >> 6;
    int lane = threadIdx.x & 63;
    if (row >= n_nodes) return;
    float a = out[row * D + lane];
    float n = nstate[row * D + lane];
    float dot = waveReduceSum64(n * a);
    out[row * D + lane] = fmaf(n, dot, -a);
}

extern "C" void kernel_launch(void* const* d_in, const int* in_sizes, int n_in,
                              void* d_out, int out_size, void* d_ws, size_t ws_size,
                              hipStream_t stream) {
    const float* state = (const float*)d_in[0];
    const int*   ind   = (const int*)d_in[1];
    const float* w1    = (const float*)d_in[2];
    const float* b1    = (const float*)d_in[3];
    const float* w2    = (const float*)d_in[4];
    const float* b2    = (const float*)d_in[5];

    int n_nodes = in_sizes[0] / D;
    int n_edges = in_sizes[1] / 2;

    float* out    = (float*)d_out;
    float* nstate = (float*)d_ws;  // 12.8 MB

    // acc lives in d_out; must be zeroed every call (harness doesn't re-poison)
    hipMemsetAsync(d_out, 0, (size_t)out_size * sizeof(float), stream);

    const int threads = 256;
    int node_blocks = (n_nodes * D + threads - 1) / threads;
    norm_kernel<<<node_blocks, threads, 0, stream>>>(state, nstate, n_nodes);

    long long total = (long long)n_edges * D;
    int edge_blocks = (int)((total + threads - 1) / threads);
    edge_kernel<<<edge_blocks, threads, 0, stream>>>(nstate, ind, w1, b1, w2, b2,
                                                     out, n_edges);

    final_kernel<<<node_blocks, threads, 0, stream>>>(nstate, out, n_nodes);
}

// Round 2
// 370.252 us; speedup vs baseline: 1.4745x; 1.4745x over previous
//
#include <hip/hip_runtime.h>

// Kuramoto graph kernel, MI355X (gfx950).
// state: [N,64] f32; ind: [E,2] int32; w1,b1,w2: [64] f32; b2: [1] f32.
// out: [N,64] f32.
//
// v2: atomic-free output. Build padded-bucket adjacency in d_ws (one scatter
// kernel, no scan), then one wave per node recomputes dot+MLP per incident
// edge and accumulates in registers; single plain store per node, projection
// fused. Fallback to v1 (edge-parallel atomics) if ws_size is too small.

#define D 64
#define CAP 128   // max degree per bucket; Poisson(50) => P(deg>=128) ~ 5e-19

// ---------- helpers ----------

__device__ __forceinline__ float grpReduce16(float v) {
    // sum across a 16-lane group (lanes with same lane>>4)
    v += __shfl_xor(v, 1, 64);
    v += __shfl_xor(v, 2, 64);
    v += __shfl_xor(v, 4, 64);
    v += __shfl_xor(v, 8, 64);
    return v;
}

__device__ __forceinline__ float waveReduceSum64(float v) {
    v += __shfl_xor(v, 32, 64);
    v += __shfl_xor(v, 16, 64);
    v += __shfl_xor(v, 8, 64);
    v += __shfl_xor(v, 4, 64);
    v += __shfl_xor(v, 2, 64);
    v += __shfl_xor(v, 1, 64);
    return v;
}

// JAX default gelu (approximate=True): 0.5*x*(1+tanh(sqrt(2/pi)*(x+0.044715 x^3)))
__device__ __forceinline__ float gelu_tanh(float x) {
    float t = 0.7978845608028654f * fmaf(0.044715f * x, x * x, x);
    float e = __expf(-2.0f * fabsf(t));
    float th = (1.0f - e) / (1.0f + e);
    return 0.5f * x * (1.0f + copysignf(th, t));
}

// ---------- common: row-normalize (16 lanes x float4 per row) ----------

__global__ void norm_kernel(const float4* __restrict__ state4,
                            float4* __restrict__ nstate4, int n_nodes) {
    int gid = blockIdx.x * blockDim.x + threadIdx.x;
    int row = gid >> 4;
    int gl  = threadIdx.x & 15;
    if (row >= n_nodes) return;
    float4 v = state4[row * 16 + gl];
    float ss = grpReduce16(fmaf(v.x, v.x, fmaf(v.y, v.y, fmaf(v.z, v.z, v.w * v.w))));
    float inv = 1.0f / sqrtf(ss);
    float4 r = {v.x * inv, v.y * inv, v.z * inv, v.w * inv};
    nstate4[row * 16 + gl] = r;
}

// ---------- v2 path: adjacency build + node-centric accumulate ----------

__global__ void scatter_kernel(const int* __restrict__ ind,
                               int* __restrict__ cursor,
                               int* __restrict__ entries, int n_edges) {
    int i = blockIdx.x * blockDim.x + threadIdx.x;
    if (i >= n_edges) return;
    int2 e = ((const int2*)ind)[i];
    int s0 = atomicAdd(&cursor[e.x], 1);
    if (s0 < CAP) entries[e.x * CAP + s0] = e.y;
    int s1 = atomicAdd(&cursor[e.y], 1);
    if (s1 < CAP) entries[e.y * CAP + s1] = e.x;
}

__global__ void __launch_bounds__(256) accum_kernel(
        const float4* __restrict__ nstate4,
        const int* __restrict__ cursor,
        const int* __restrict__ entries,
        const float4* __restrict__ w1_4,
        const float4* __restrict__ b1_4,
        const float4* __restrict__ w2_4,
        const float* __restrict__ b2,
        float4* __restrict__ out4, int n_nodes) {
    int node = blockIdx.x * (blockDim.x >> 6) + (threadIdx.x >> 6);
    if (node >= n_nodes) return;
    int lane = threadIdx.x & 63;
    int grp  = lane >> 4;   // which of 4 neighbors this iteration
    int gl   = lane & 15;   // dims [4*gl .. 4*gl+3]

    float4 my = nstate4[node * 16 + gl];
    float4 W1 = w1_4[gl];
    float4 B1 = b1_4[gl];
    float4 W2 = w2_4[gl];
    float  B2 = b2[0];

    int deg = min(cursor[node], CAP);
    const int* ebase = entries + (long long)node * CAP;

    float4 acc = {0.f, 0.f, 0.f, 0.f};
    for (int k0 = 0; k0 < deg; k0 += 4) {
        int idx = k0 + grp;
        bool valid = idx < deg;
        int nbr = valid ? ebase[idx] : 0;
        float4 x = nstate4[nbr * 16 + gl];

        // s = <n_node, n_nbr>  (16-lane reduce, per group)
        float p = fmaf(my.x, x.x, fmaf(my.y, x.y, fmaf(my.z, x.z, my.w * x.w)));
        float s = grpReduce16(p);

        // dE = sum_d gelu(s*w1+b1)*w2 + b2   (each lane: 4 dims)
        float h = gelu_tanh(fmaf(s, W1.x, B1.x)) * W2.x;
        h      += gelu_tanh(fmaf(s, W1.y, B1.y)) * W2.y;
        h      += gelu_tanh(fmaf(s, W1.z, B1.z)) * W2.z;
        h      += gelu_tanh(fmaf(s, W1.w, B1.w)) * W2.w;
        float dE = grpReduce16(h) + B2;
        if (!valid) dE = 0.0f;

        acc.x = fmaf(dE, x.x, acc.x);
        acc.y = fmaf(dE, x.y, acc.y);
        acc.z = fmaf(dE, x.z, acc.z);
        acc.w = fmaf(dE, x.w, acc.w);
    }

    // sum the 4 groups' partial accumulators (each covers all 64 dims)
    acc.x += __shfl_xor(acc.x, 16, 64); acc.x += __shfl_xor(acc.x, 32, 64);
    acc.y += __shfl_xor(acc.y, 16, 64); acc.y += __shfl_xor(acc.y, 32, 64);
    acc.z += __shfl_xor(acc.z, 16, 64); acc.z += __shfl_xor(acc.z, 32, 64);
    acc.w += __shfl_xor(acc.w, 16, 64); acc.w += __shfl_xor(acc.w, 32, 64);

    // out = -acc + n * <n, acc>
    float p = fmaf(my.x, acc.x, fmaf(my.y, acc.y, fmaf(my.z, acc.z, my.w * acc.w)));
    float dot2 = grpReduce16(p);
    float4 r;
    r.x = fmaf(my.x, dot2, -acc.x);
    r.y = fmaf(my.y, dot2, -acc.y);
    r.z = fmaf(my.z, dot2, -acc.z);
    r.w = fmaf(my.w, dot2, -acc.w);
    if (grp == 0) out4[node * 16 + gl] = r;
}

// ---------- v1 fallback path (edge-parallel, atomic output) ----------

__global__ void edge_kernel(const float* __restrict__ nstate,
                            const int* __restrict__ ind,
                            const float* __restrict__ w1,
                            const float* __restrict__ b1,
                            const float* __restrict__ w2,
                            const float* __restrict__ b2,
                            float* __restrict__ acc, int n_edges) {
    int gid = blockIdx.x * blockDim.x + threadIdx.x;
    int edge = gid >> 6;
    int lane = threadIdx.x & 63;
    if (edge >= n_edges) return;
    const int2 e = ((const int2*)ind)[edge];
    float sv = nstate[e.x * D + lane];
    float dv = nstate[e.y * D + lane];
    float s = waveReduceSum64(sv * dv);
    float x = fmaf(s, w1[lane], b1[lane]);
    float h = gelu_tanh(x) * w2[lane];
    float dE = waveReduceSum64(h) + b2[0];
    atomicAdd(&acc[e.x * D + lane], dE * dv);
    atomicAdd(&acc[e.y * D + lane], dE * sv);
}

__global__ void final_kernel(const float* __restrict__ nstate,
                             float* __restrict__ out, int n_nodes) {
    int gid = blockIdx.x * blockDim.x + threadIdx.x;
    int row = gid >> 6;
    int lane = threadIdx.x & 63;
    if (row >= n_nodes) return;
    float a = out[row * D + lane];
    float n = nstate[row * D + lane];
    float dot = waveReduceSum64(n * a);
    out[row * D + lane] = fmaf(n, dot, -a);
}

// ---------- launch ----------

extern "C" void kernel_launch(void* const* d_in, const int* in_sizes, int n_in,
                              void* d_out, int out_size, void* d_ws, size_t ws_size,
                              hipStream_t stream) {
    const float* state = (const float*)d_in[0];
    const int*   ind   = (const int*)d_in[1];
    const float* w1    = (const float*)d_in[2];
    const float* b1    = (const float*)d_in[3];
    const float* w2    = (const float*)d_in[4];
    const float* b2    = (const float*)d_in[5];

    int n_nodes = in_sizes[0] / D;
    int n_edges = in_sizes[1] / 2;

    // workspace layout
    size_t nstate_bytes  = (size_t)n_nodes * D * sizeof(float);
    size_t cursor_off    = (nstate_bytes + 255) & ~(size_t)255;
    size_t cursor_bytes  = (size_t)n_nodes * sizeof(int);
    size_t entries_off   = (cursor_off + cursor_bytes + 255) & ~(size_t)255;
    size_t entries_bytes = (size_t)n_nodes * CAP * sizeof(int);
    size_t needed        = entries_off + entries_bytes;

    float* nstate = (float*)d_ws;
    const int threads = 256;

    // normalize rows (16 lanes x float4 per row)
    int norm_blocks = (n_nodes * 16 + threads - 1) / threads;
    norm_kernel<<<norm_blocks, threads, 0, stream>>>(
        (const float4*)state, (float4*)nstate, n_nodes);

    if (ws_size >= needed) {
        int* cursor  = (int*)((char*)d_ws + cursor_off);
        int* entries = (int*)((char*)d_ws + entries_off);
        hipMemsetAsync(cursor, 0, cursor_bytes, stream);

        int sc_blocks = (n_edges + threads - 1) / threads;
        scatter_kernel<<<sc_blocks, threads, 0, stream>>>(ind, cursor, entries, n_edges);

        int acc_blocks = (n_nodes + (threads / 64) - 1) / (threads / 64);
        accum_kernel<<<acc_blocks, threads, 0, stream>>>(
            (const float4*)nstate, cursor, entries,
            (const float4*)w1, (const float4*)b1, (const float4*)w2, b2,
            (float4*)d_out, n_nodes);
    } else {
        // fallback: edge-parallel with atomics into d_out
        hipMemsetAsync(d_out, 0, (size_t)out_size * sizeof(float), stream);
        long long total = (long long)n_edges * D;
        int edge_blocks = (int)((total + threads - 1) / threads);
        edge_kernel<<<edge_blocks, threads, 0, stream>>>(
            nstate, ind, w1, b1, w2, b2, (float*)d_out, n_edges);
        int node_blocks = (n_nodes * D + threads - 1) / threads;
        final_kernel<<<node_blocks, threads, 0, stream>>>(nstate, (float*)d_out, n_nodes);
    }
}